// Round 1
// 71.314 us; speedup vs baseline: 1.0351x; 1.0351x over previous
//
#include <hip/hip_runtime.h>
#include <math.h>

#define B 64
#define P 1024
#define L 16
#define H 256
#define K 64

__device__ __forceinline__ float wsum(float v){
  #pragma unroll
  for (int o = 32; o >= 1; o >>= 1) v += __shfl_xor(v, o, 64);
  return v;
}
__device__ __forceinline__ float wmaxr(float v){
  #pragma unroll
  for (int o = 32; o >= 1; o >>= 1) v = fmaxf(v, __shfl_xor(v, o, 64));
  return v;
}
__device__ __forceinline__ void wargmax(float &v, int &i){
  #pragma unroll
  for (int o = 32; o >= 1; o >>= 1){
    float v2 = __shfl_xor(v, o, 64);
    int   i2 = __shfl_xor(i, o, 64);
    if (v2 > v || (v2 == v && i2 < i)){ v = v2; i = i2; }
  }
}
__device__ __forceinline__ unsigned fkey(float f){
  unsigned b = __float_as_uint(f);
  return (b & 0x80000000u) ? ~b : (b | 0x80000000u);
}

// ---------------- kernel 1: radix-select top-64 per batch + IoU + w ----------------
__global__ __launch_bounds__(256) void k_topk_iou(
    const float* __restrict__ pred_center, const float* __restrict__ pred_size,
    const float* __restrict__ obj, const float* __restrict__ ref_center,
    const int* __restrict__ ref_cls, const float* __restrict__ ref_res,
    const float* __restrict__ mean_sz, const int* __restrict__ epoch_p,
    int* __restrict__ inds, float* __restrict__ iou_ws, float* __restrict__ w_ws)
{
  __shared__ int hist[256];
  __shared__ int s_digit, s_cum;
  __shared__ int waveTot[4];
  __shared__ int sel[K];
  __shared__ float ctrS[K][3], szS[K][3];
  int b = blockIdx.x, tid = threadIdx.x, lane = tid & 63, wave = tid >> 6;

  // each thread owns 4 contiguous proposals: indices 4*tid .. 4*tid+3
  const float4* o4 = (const float4*)(obj + (size_t)b*P*2);
  float4 va = o4[tid*2], vb = o4[tid*2+1];
  unsigned kj[4] = { fkey(va.y - va.x), fkey(va.w - va.z),
                     fkey(vb.y - vb.x), fkey(vb.w - vb.z) };

  // 4-pass radix select (8-bit digits, high to low) for the 64th-largest key.
  unsigned prefix = 0; int rem = K;
  for (int pass = 0; pass < 4; ++pass){
    int shift = 24 - pass*8;
    hist[tid] = 0;
    __syncthreads();
    #pragma unroll
    for (int j = 0; j < 4; ++j){
      unsigned kk = kj[j];
      bool cand = (pass == 0) || ((kk >> (shift + 8)) == prefix);
      if (cand) atomicAdd(&hist[(kk >> shift) & 0xff], 1);
    }
    __syncthreads();
    // thread tid owns bin d = 255 - tid; inclusive scan over tid = suffix sum over d
    int d = 255 - tid;
    int h = hist[d];
    int s = h;
    #pragma unroll
    for (int o = 1; o < 64; o <<= 1){ int t = __shfl_up(s, o, 64); if (lane >= o) s += t; }
    if (lane == 63) waveTot[wave] = s;
    __syncthreads();
    #pragma unroll
    for (int q = 0; q < 3; ++q) if (q < wave) s += waveTot[q];
    // s = count of keys with digit >= d among candidates
    if (s >= rem && s - h < rem){ s_digit = d; s_cum = s - h; }
    __syncthreads();
    prefix = (prefix << 8) | (unsigned)s_digit;
    rem -= s_cum;
    __syncthreads();
  }
  unsigned T = prefix;      // exact key of the cut
  int remFinal = rem;       // how many ==T to take (lowest index first)

  // deterministic compaction: scan #1 ranks the ==T keys by index
  int eqc = 0;
  #pragma unroll
  for (int j = 0; j < 4; ++j) eqc += (kj[j] == T) ? 1 : 0;
  int v = eqc;
  #pragma unroll
  for (int o = 1; o < 64; o <<= 1){ int t = __shfl_up(v, o, 64); if (lane >= o) v += t; }
  if (lane == 63) waveTot[wave] = v;
  __syncthreads();
  int off = 0;
  for (int q = 0; q < wave; ++q) off += waveTot[q];
  int e = off + v - eqc;    // exclusive prefix of eq-count
  __syncthreads();          // waveTot reuse

  int selc = 0; bool ch[4];
  #pragma unroll
  for (int j = 0; j < 4; ++j){
    bool g = kj[j] > T;
    bool q = (kj[j] == T) && (e < remFinal);
    if (kj[j] == T) e++;
    ch[j] = g || q; selc += ch[j] ? 1 : 0;
  }
  v = selc;
  #pragma unroll
  for (int o = 1; o < 64; o <<= 1){ int t = __shfl_up(v, o, 64); if (lane >= o) v += t; }
  if (lane == 63) waveTot[wave] = v;
  __syncthreads();
  off = 0;
  for (int q = 0; q < wave; ++q) off += waveTot[q];
  int slot = off + v - selc;
  #pragma unroll
  for (int j = 0; j < 4; ++j) if (ch[j]) sel[slot++] = tid*4 + j;
  __syncthreads();

  if (tid < K){
    int idx = sel[tid];
    inds[b*K + tid] = idx;
    #pragma unroll
    for (int dd = 0; dd < 3; ++dd){
      ctrS[tid][dd] = pred_center[((size_t)b*P + idx)*3 + dd];
      szS [tid][dd] = pred_size [((size_t)b*P + idx)*3 + dd];
    }
  }
  __syncthreads();

  int ep = epoch_p[0];
  float pr = ep <= 0 ? 0.f : (ep >= 80 ? 1.f : ep / 80.f);
  float thr = 0.05f + 0.3f * pr;
  float gamma = 1.f + 2.f * pr;

  for (int l = wave; l < L; l += 4){
    int cls = ref_cls[b*L + l];
    float gs[3], gc[3]; float volg = 1.f;
    #pragma unroll
    for (int dd = 0; dd < 3; ++dd){
      gs[dd] = mean_sz[cls*3+dd] + ref_res[((size_t)b*L+l)*3+dd] + 0.01f;
      gc[dd] = ref_center[((size_t)b*L+l)*3+dd];
      volg *= gs[dd];
    }
    int k = lane;
    float inter = 1.f, volp = 1.f;
    #pragma unroll
    for (int dd = 0; dd < 3; ++dd){
      float pc = ctrS[k][dd], ps = szS[k][dd];
      float lo = fmaxf(gc[dd]-gs[dd]*0.5f, pc-ps*0.5f);
      float hi = fminf(gc[dd]+gs[dd]*0.5f, pc+ps*0.5f);
      inter *= fmaxf(hi-lo, 0.f);
      volp *= ps;
    }
    float iou = inter / (volg + volp - inter + 1e-7f);
    float wv = (iou >= thr) ? powf(iou, gamma) : 0.f;
    float S = wsum(wv);
    float av = iou; int ai = k;
    wargmax(av, ai);
    float wfin = (S < 1e-6f) ? ((k == ai) ? 1.f : 0.f) : wv;
    iou_ws[((size_t)b*L + l)*K + k] = iou;
    w_ws  [((size_t)b*L + l)*K + k] = wfin;
  }
}

// ---------------- kernel 2: fused 3x GEMM  C = A @ W^T (gather fused) ----------------
// blocks 0..63: boxr = feat[inds] @ Wpc^T ; 64..127: boxri = feat[inds] @ Wpci^T ;
// 128..143: texr = lang_emb @ Wtext^T.  64x64 tiles, 4x4 per thread.
__global__ __launch_bounds__(256) void k_gemm(
    const float* __restrict__ bbox_feature, const int* __restrict__ inds,
    const float* __restrict__ lang_emb,
    const float* __restrict__ Wpc, const float* __restrict__ Wpci,
    const float* __restrict__ Wtext,
    float* __restrict__ boxr, float* __restrict__ boxri, float* __restrict__ texr)
{
  __shared__ float As[16][68], Ws[16][68];
  int gb = blockIdx.x;
  const float *W; float *C; int m0; bool gat;
  if (gb < 64)       { W = Wpc;   C = boxr;  m0 = gb*64;       gat = true;  }
  else if (gb < 128) { W = Wpci;  C = boxri; m0 = (gb-64)*64;  gat = true;  }
  else               { W = Wtext; C = texr;  m0 = (gb-128)*64; gat = false; }
  int bcol = blockIdx.y * 64;
  int tid = threadIdx.x;
  int lr = tid >> 2, lc = (tid & 3) * 4;
  int tr = tid >> 4, tc = tid & 15;
  int r = m0 + lr;
  const float* Arow = gat ? bbox_feature + ((size_t)(r >> 6)*P + inds[r])*H
                          : lang_emb + (size_t)r*H;
  const float* Wrow = W + (size_t)(bcol + lr)*H;
  float acc[4][4] = {};
  for (int h0 = 0; h0 < H; h0 += 16){
    float4 av = *(const float4*)&Arow[h0 + lc];
    float4 wv = *(const float4*)&Wrow[h0 + lc];
    As[lc+0][lr]=av.x; As[lc+1][lr]=av.y; As[lc+2][lr]=av.z; As[lc+3][lr]=av.w;
    Ws[lc+0][lr]=wv.x; Ws[lc+1][lr]=wv.y; Ws[lc+2][lr]=wv.z; Ws[lc+3][lr]=wv.w;
    __syncthreads();
    #pragma unroll
    for (int h = 0; h < 16; ++h){
      float4 a = *(const float4*)&As[h][tr*4];
      float4 w = *(const float4*)&Ws[h][tc*4];
      float aa[4] = {a.x,a.y,a.z,a.w};
      float ww[4] = {w.x,w.y,w.z,w.w};
      #pragma unroll
      for (int i = 0; i < 4; ++i)
        #pragma unroll
        for (int j = 0; j < 4; ++j) acc[i][j] += aa[i]*ww[j];
    }
    __syncthreads();
  }
  #pragma unroll
  for (int i = 0; i < 4; ++i){
    float4 v = make_float4(acc[i][0],acc[i][1],acc[i][2],acc[i][3]);
    *(float4*)&C[(size_t)(m0+tr*4+i)*H + bcol + tc*4] = v;
  }
}

// ---------------- kernel 3: contrast losses, register-resident softmax ----------------
// blocks 0..63: lang loss for batch b.
// blocks 64..319: iou loss; idx=blk-64 -> b=idx>>2, strip of 16 simi rows k0=(idx&3)*16.
// Row norms are accumulated in-register during GEMM staging (k_norms eliminated).
__global__ __launch_bounds__(256) void k_contrast(
    const float* __restrict__ texr, const float* __restrict__ boxr,
    const float* __restrict__ boxri,
    const float* __restrict__ iou_ws, const float* __restrict__ w_ws,
    const int* __restrict__ lang_num, const float* __restrict__ log_inv_tau,
    const int* __restrict__ epoch_p, float* __restrict__ part)
{
  __shared__ __align__(16) float boxC[32*68];   // transposed [h][row] chunk
  __shared__ __align__(16) float texC[32*16];
  __shared__ float red[4];
  int tid = threadIdx.x, lane = tid & 63, wave = tid >> 6;
  int ep = epoch_p[0];
  float pr = ep <= 0 ? 0.f : (ep >= 80 ? 1.f : ep / 80.f);
  float min_tau = fmaxf(0.08f - 0.04f*pr, 1e-6f);
  float itau = fminf(fminf(expf(log_inv_tau[0]), 100.f), 1.f/min_tau);

  if (blockIdx.x < 64){
    // ---------------- lang branch: sim = tex(16xH) @ box(64xH)^T ----------------
    int b = blockIdx.x;
    const float4* boxr4 = (const float4*)(boxr + (size_t)b*K*H);
    const float4* texr4 = (const float4*)(texr + (size_t)b*L*H);
    float acc[4] = {0,0,0,0}, nt2[4] = {0,0,0,0};
    float nb2 = 0.f;
    for (int h0 = 0; h0 < H; h0 += 32){
      for (int i4 = tid; i4 < 512; i4 += 256){
        int row = i4 >> 3, cg = i4 & 7;
        float4 v = boxr4[row*64 + (h0>>2) + cg];
        boxC[(cg*4+0)*68+row]=v.x; boxC[(cg*4+1)*68+row]=v.y;
        boxC[(cg*4+2)*68+row]=v.z; boxC[(cg*4+3)*68+row]=v.w;
      }
      if (tid < 128){
        int row = tid >> 3, cg = tid & 7;
        float4 v = texr4[row*64 + (h0>>2) + cg];
        texC[(cg*4+0)*16+row]=v.x; texC[(cg*4+1)*16+row]=v.y;
        texC[(cg*4+2)*16+row]=v.z; texC[(cg*4+3)*16+row]=v.w;
      }
      __syncthreads();
      #pragma unroll
      for (int h = 0; h < 32; ++h){
        float bx = boxC[h*68 + lane];                       // box row = lane
        float4 tv = *(const float4*)&texC[h*16 + wave*4];   // tex rows wave*4..+3
        acc[0] += tv.x*bx; acc[1] += tv.y*bx; acc[2] += tv.z*bx; acc[3] += tv.w*bx;
        nb2 += bx*bx;
        nt2[0]+=tv.x*tv.x; nt2[1]+=tv.y*tv.y; nt2[2]+=tv.z*tv.z; nt2[3]+=tv.w*tv.w;
      }
      __syncthreads();
    }
    float nb = fmaxf(sqrtf(nb2), 1e-12f);
    int ln = lang_num[b];
    float bacc = 0.f;
    #pragma unroll
    for (int i = 0; i < 4; ++i){
      int l = wave*4 + i;
      if (l < ln){                          // wave-uniform: skip masked rows
        float sv = acc[i] / (fmaxf(sqrtf(nt2[i]), 1e-12f) * nb);
        float wv  = w_ws [((size_t)b*L + l)*K + lane];
        float iou = iou_ws[((size_t)b*L + l)*K + lane];
        float S2 = wsum(wv);
        float target = wv / (S2 + 1e-6f);
        float tsum = S2 / (S2 + 1e-6f);
        float t2 = target / (tsum + 1e-6f);
        float z = sv * itau;
        float zmax = wmaxr(z);
        float se = wsum(expf(z - zmax));
        float lp = z - zmax - logf(se);
        float ce = -wsum(t2 * lp);
        bool neg = iou < 0.05f;
        float sneg = wmaxr(neg ? sv : -INFINITY);
        int anyneg = __any(neg);
        float spos = wsum(sv * target);
        float rank = anyneg ? fmaxf(0.2f - spos + sneg, 0.f) : 0.f;
        bacc += ce + 0.5f*rank;
      }
    }
    if (lane == 0) red[wave] = bacc;
    __syncthreads();
    if (tid == 0) part[b] = red[0]+red[1]+red[2]+red[3];
  } else {
    // ---------------- iou branch: strip of 16 simi rows ----------------
    int idx = blockIdx.x - 64;
    int b = idx >> 2, k0 = (idx & 3) * 16;
    const float4* bi4 = (const float4*)(boxri + (size_t)b*K*H);
    float acc[4] = {0,0,0,0}, nk2[4] = {0,0,0,0};
    float nm2 = 0.f;
    for (int h0 = 0; h0 < H; h0 += 32){
      for (int i4 = tid; i4 < 512; i4 += 256){
        int row = i4 >> 3, cg = i4 & 7;
        float4 v = bi4[row*64 + (h0>>2) + cg];
        boxC[(cg*4+0)*68+row]=v.x; boxC[(cg*4+1)*68+row]=v.y;
        boxC[(cg*4+2)*68+row]=v.z; boxC[(cg*4+3)*68+row]=v.w;
      }
      __syncthreads();
      #pragma unroll
      for (int h = 0; h < 32; ++h){
        float bx = boxC[h*68 + lane];                               // m = lane
        float4 kq = *(const float4*)&boxC[h*68 + k0 + wave*4];      // k rows (bcast)
        acc[0] += kq.x*bx; acc[1] += kq.y*bx; acc[2] += kq.z*bx; acc[3] += kq.w*bx;
        nm2 += bx*bx;
        nk2[0]+=kq.x*kq.x; nk2[1]+=kq.y*kq.y; nk2[2]+=kq.z*kq.z; nk2[3]+=kq.w*kq.w;
      }
      __syncthreads();
    }
    float nm = fmaxf(sqrtf(nm2), 1e-12f);
    float lp[4];
    #pragma unroll
    for (int i = 0; i < 4; ++i){
      float sv = acc[i] / (fmaxf(sqrtf(nk2[i]), 1e-12f) * nm);
      float z = sv * itau;
      float zmax = wmaxr(z);
      float se = wsum(expf(z - zmax));
      lp[i] = z - zmax - logf(se);          // logp row k0+wave*4+i, col m=lane
    }
    int ln = lang_num[b];
    float bacc = 0.f;
    for (int l = 0; l < ln; ++l){
      float wv = w_ws[((size_t)b*L + l)*K + lane];
      float S = wsum(wv);
      float contrib = 0.f;
      #pragma unroll
      for (int i = 0; i < 4; ++i){
        float wk = __shfl(wv, k0 + wave*4 + i, 64);
        float g = wsum(wv * lp[i]);
        float a = wk * S;
        float c = wk / ((a + 1e-6f) * (a/(a + 1e-6f) + 1e-6f));
        contrib += c * g;
      }
      bacc += -contrib * (1.f/64.f);
    }
    if (lane == 0) red[wave] = bacc;
    __syncthreads();
    if (tid == 0) part[64 + idx] = red[0]+red[1]+red[2]+red[3];
  }
}

// ---------------- kernel 4: deterministic final reduce ----------------
__global__ __launch_bounds__(256) void k_final(const float* __restrict__ part,
                                               float* __restrict__ out)
{
  __shared__ float red[5];
  int tid = threadIdx.x, lane = tid & 63, wave = tid >> 6;
  float v = part[64 + tid];                  // 256 iou partials
  v = wsum(v);
  if (lane == 0) red[wave] = v;
  float u = (wave == 0) ? part[tid] : 0.f;   // 64 lang partials
  u = wsum(u);
  if (tid == 0) red[4] = u;
  __syncthreads();
  if (tid == 0){
    out[0] = red[4] * (1.f/64.f);
    out[1] = (red[0]+red[1]+red[2]+red[3]) * (1.f/64.f);
  }
}

extern "C" void kernel_launch(void* const* d_in, const int* in_sizes, int n_in,
                              void* d_out, int out_size, void* d_ws, size_t ws_size,
                              hipStream_t stream)
{
  const float* pred_center = (const float*)d_in[0];
  const float* pred_size   = (const float*)d_in[1];
  const float* bbox_feature= (const float*)d_in[2];
  const float* obj         = (const float*)d_in[3];
  const float* lang_emb    = (const float*)d_in[4];
  const int*   lang_num    = (const int*)d_in[5];
  const float* ref_center  = (const float*)d_in[6];
  const int*   ref_cls     = (const int*)d_in[7];
  const float* ref_res     = (const float*)d_in[8];
  const float* mean_sz     = (const float*)d_in[9];
  const float* Wtext       = (const float*)d_in[10];
  const float* Wpc         = (const float*)d_in[11];
  const float* Wpci        = (const float*)d_in[12];
  const float* lit         = (const float*)d_in[13];
  const int*   epoch       = (const int*)d_in[14];

  float* ws = (float*)d_ws;
  int*   inds   = (int*)ws;                 // B*K ints
  float* iou_ws = ws + 4096;                // B*L*K
  float* w_ws   = iou_ws + B*L*K;           // B*L*K
  float* texr   = w_ws + B*L*K;             // B*L*H
  float* boxr   = texr + (size_t)B*L*H;     // B*K*H
  float* boxri  = boxr + (size_t)B*K*H;     // B*K*H
  float* part   = boxri + (size_t)B*K*H;    // 320 partials (64 lang + 256 iou)

  k_topk_iou<<<B, 256, 0, stream>>>(pred_center, pred_size, obj, ref_center,
                                    ref_cls, ref_res, mean_sz, epoch,
                                    inds, iou_ws, w_ws);
  k_gemm<<<dim3(144, 4), 256, 0, stream>>>(bbox_feature, inds, lang_emb,
                                           Wpc, Wpci, Wtext, boxr, boxri, texr);
  k_contrast<<<320, 256, 0, stream>>>(texr, boxr, boxri,
                                      iou_ws, w_ws, lang_num, lit, epoch, part);
  k_final<<<1, 256, 0, stream>>>(part, (float*)d_out);
}